// Round 7
// baseline (740.053 us; speedup 1.0000x reference)
//
#include <hip/hip_runtime.h>
#include <hip/hip_cooperative_groups.h>

namespace cg = cooperative_groups;

// Problem constants (from reference)
constexpr int N_NODES = 100000;
constexpr int N_EDGES = 1000000;
constexpr int D_NODE  = 64;
constexpr int D_EDGE  = 32;
constexpr int D_GLOB  = 32;
constexpr int OUT_DIM = 64;
constexpr int K1 = 2*D_NODE + D_EDGE + D_GLOB; // 192
constexpr int K2 = D_NODE + OUT_DIM + D_GLOB;  // 160

typedef _Float16 f16x8 __attribute__((ext_vector_type(8)));
typedef unsigned short ushort8_t __attribute__((ext_vector_type(8)));
typedef float floatx16 __attribute__((ext_vector_type(16)));

// LDS feature-tile row stride (f16 elems): 400 B rows, 16B-aligned.
constexpr int FS = 200;

// d_ws layout (bytes), all 16B-aligned:
//   [0,     24576)  W1t f16 [64][192]   (transposed: [n][k])
//   [24576, 45056)  W2t f16 [64][160]
//   [45056, 46080)  ub  f16 [16][32]
//   [46080, ...  )  xb  f16 [100000][64]  (12.8 MB)
// agg (f16 [100000][64]) lives INSIDE d_out: row n = first 128 B of out row n.
constexpr size_t WS_W1T = 0;
constexpr size_t WS_W2T = 24576;
constexpr size_t WS_UB  = 45056;
constexpr size_t WS_XB  = 46080;

__device__ inline unsigned pack_f2(float a, float b) {
    auto h = __builtin_amdgcn_cvt_pkrtz(a, b);    // v_cvt_pkrtz_f16_f32
    return __builtin_bit_cast(unsigned, h);
}

// ---------------------------------------------------------------------------
// fused_all: persistent-block cooperative kernel.
//   P0 (phase<=0): f16-convert x,u,W1t,W2t; zero d_out (memset dispatch gone).
//   P1 (phase==1|-1): edge tiles, grid-stride. Body = R5's proven 167 us
//     structure: early-ea prefetch, gather, 32x32x16 MFMA, LDS transpose
//     round-trip, pk_add_f16 epilogue (2 agg rows / wave-instr locality).
//   P2 (phase==2|-1): node tiles, grid-stride (R5 node body).
// phase==-1 -> single cooperative launch with grid syncs between phases.
// phase in {0,1,2} -> fallback: three normal launches, same code.
// ---------------------------------------------------------------------------
__global__ __launch_bounds__(256, 6) void fused_all(
    const float* __restrict__ x, const int* __restrict__ ei,
    const float* __restrict__ ea, const float* __restrict__ u,
    const int* __restrict__ batch,
    const float* __restrict__ W1, const float* __restrict__ b1,
    const float* __restrict__ W2, const float* __restrict__ b2,
    unsigned short* __restrict__ w1t, unsigned short* __restrict__ w2t,
    unsigned short* __restrict__ ub, unsigned short* __restrict__ xb,
    float* __restrict__ out, int phase)
{
    __shared__ __align__(16) unsigned short smem[64 * FS]; // 25600 B
    __shared__ int s_dst[64];
    __shared__ int s_src[64];
    __shared__ int s_b[64];

    const int tid  = threadIdx.x;
    const int lane = tid & 63;
    const int wv   = tid >> 6;
    const int eh   = wv >> 1;
    const int nh   = wv & 1;
    const int col  = lane & 31;
    const int half = lane >> 5;
    const int gsz  = gridDim.x * 256;
    const int gt   = blockIdx.x * 256 + tid;

    // ---------------- P0: prep + zero out ----------------
    if (phase <= 0) {
        const float4* x4 = (const float4*)x;
        for (int i = gt; i < N_NODES * 16; i += gsz) {      // x -> f16 xb
            float4 v = x4[i];
            uint2 pk;
            pk.x = pack_f2(v.x, v.y);
            pk.y = pack_f2(v.z, v.w);
            *(uint2*)&xb[i * 4] = pk;
        }
        const uint4 z = {0, 0, 0, 0};
        uint4* o4 = (uint4*)out;
        for (int i = gt; i < N_NODES * 16; i += gsz)        // zero agg/out
            o4[i] = z;
        for (int i = gt; i < K1 * 64; i += gsz) {           // W1 [k][n]->[n][k]
            int k = i >> 6, n = i & 63;
            _Float16 h = (_Float16)W1[i];
            w1t[n * K1 + k] = __builtin_bit_cast(unsigned short, h);
        }
        for (int i = gt; i < K2 * 64; i += gsz) {           // W2 [k][n]->[n][k]
            int k = i >> 6, n = i & 63;
            _Float16 h = (_Float16)W2[i];
            w2t[n * K2 + k] = __builtin_bit_cast(unsigned short, h);
        }
        for (int i = gt; i < 16 * D_GLOB; i += gsz) {       // u
            _Float16 h = (_Float16)u[i];
            ub[i] = __builtin_bit_cast(unsigned short, h);
        }
    }
    if (phase == -1) { __threadfence(); cg::this_grid().sync(); }

    // ---------------- P1: edge phase ----------------
    if (phase == -1 || phase == 1) {
        const float4* ea4 = (const float4*)ea;

        // Hoisted per-thread constants (valid for every tile)
        f16x8 Wf[12];
        #pragma unroll
        for (int s = 0; s < 12; ++s)
            Wf[s] = __builtin_bit_cast(f16x8,
                *(const ushort8_t*)&w1t[(nh*32 + col) * K1 + s*16 + half*8]);
        const int chp = (lane & 31) * 2;
        const float2 bv = *(const float2*)&b1[chp];

        for (int tile = blockIdx.x; tile < N_EDGES / 64; tile += gridDim.x) {
            __syncthreads();               // prior tile's epilogue readers done

            if (tid < 64) {
                int e = tile * 64 + tid;
                int d = ei[N_EDGES + e];   // dst
                s_dst[tid] = d;
                s_src[tid] = ei[e];        // src
                s_b[tid]   = batch[d];
            }
            // ea chunks depend only on tile: issue before the index barrier.
            {
                int el = tid >> 2, c = tid & 3;
                float4 v0 = ea4[(tile*64 + el) * 8 + c * 2 + 0];
                float4 v1 = ea4[(tile*64 + el) * 8 + c * 2 + 1];
                uint4 pk;
                pk.x = pack_f2(v0.x, v0.y); pk.y = pack_f2(v0.z, v0.w);
                pk.z = pack_f2(v1.x, v1.y); pk.w = pack_f2(v1.z, v1.w);
                *(uint4*)&smem[el * FS + (16 + c) * 8] = pk;
            }
            __syncthreads();               // indices visible

            // Gather 20 chunks/edge (x[dst]:8 | x[src]:8 | u:4), 5/thread
            for (int q = tid; q < 64 * 20; q += 256) {
                int el = q / 20;
                int c  = q - el * 20;
                uint4 pk;
                if (c < 8)       pk = *(const uint4*)&xb[s_dst[el] * 64 + c * 8];
                else if (c < 16) pk = *(const uint4*)&xb[s_src[el] * 64 + (c - 8) * 8];
                else             pk = *(const uint4*)&ub[s_b[el] * 32 + (c - 16) * 8];
                *(uint4*)&smem[el * FS + (c < 16 ? c : c + 4) * 8] = pk;
            }
            __syncthreads();               // feat visible

            // D[edge][ch] = feat @ W1
            floatx16 acc = {0,0,0,0,0,0,0,0,0,0,0,0,0,0,0,0};
            #pragma unroll
            for (int s = 0; s < 12; ++s) {
                f16x8 a = __builtin_bit_cast(f16x8,
                    *(const ushort8_t*)&smem[(eh*32 + col) * FS + s*16 + half*8]);
                acc = __builtin_amdgcn_mfma_f32_32x32x16_f16(a, Wf[s], acc, 0, 0, 0);
            }

            // Stage msg tile f32 [64 edge][64 ch] into LDS
            __syncthreads();               // all waves done reading feat tile
            float* smemf = (float*)smem;
            #pragma unroll
            for (int r = 0; r < 16; ++r) {
                int e = eh*32 + (r & 3) + 8*(r >> 2) + 4*half;
                smemf[e * 64 + nh*32 + col] = acc[r];
            }
            __syncthreads();

            // Transposed epilogue: 2 agg rows / wave-instr, pk_add_f16
            #pragma unroll
            for (int it = 0; it < 8; ++it) {
                int e = wv*16 + it*2 + half;
                float2 m = *(const float2*)&smemf[e * 64 + chp];
                float v0 = m.x + bv.x; v0 = v0 > 0.f ? v0 : 0.f;
                float v1 = m.y + bv.y; v1 = v1 > 0.f ? v1 : 0.f;
                unsigned pk = pack_f2(v0, v1);
                unsigned short* p = (unsigned short*)out + (size_t)s_dst[e] * 128 + chp;
                asm volatile("global_atomic_pk_add_f16 %0, %1, off"
                             :: "v"(p), "v"(pk) : "memory");
            }
        }
    }
    if (phase == -1) { __threadfence(); cg::this_grid().sync(); }

    // ---------------- P2: node phase ----------------
    if (phase == -1 || phase == 2) {
        f16x8 Bf[10];
        #pragma unroll
        for (int s = 0; s < 10; ++s)
            Bf[s] = __builtin_bit_cast(f16x8,
                *(const ushort8_t*)&w2t[(nh*32 + col) * K2 + s*16 + half*8]);
        const float b2v = b2[nh*32 + col];
        const unsigned short* aggb = (const unsigned short*)out;

        for (int t = blockIdx.x; t < (N_NODES + 63) / 64; t += gridDim.x) {
            const int base = t * 64;
            __syncthreads();

            if (tid < 64) {
                int n = base + tid;
                s_b[tid] = (n < N_NODES) ? batch[n] : 0;
            }
            __syncthreads();

            // Gather: 64 nodes x 20 chunks (x:8 | agg:8 | u:4)
            for (int q = tid; q < 64 * 20; q += 256) {
                int nl = q / 20;
                int c  = q - nl * 20;
                int n  = base + nl;
                uint4 pk;
                if (n >= N_NODES) pk = uint4{0, 0, 0, 0};
                else if (c < 8)   pk = *(const uint4*)&xb[n * 64 + c * 8];
                else if (c < 16)  pk = *(const uint4*)&aggb[(size_t)n * 128 + (c - 8) * 8];
                else              pk = *(const uint4*)&ub[s_b[nl] * 32 + (c - 16) * 8];
                *(uint4*)&smem[nl * FS + c * 8] = pk;
            }
            __syncthreads();

            floatx16 acc = {0,0,0,0,0,0,0,0,0,0,0,0,0,0,0,0};
            #pragma unroll
            for (int s = 0; s < 10; ++s) {
                f16x8 a = __builtin_bit_cast(f16x8,
                    *(const ushort8_t*)&smem[(eh*32 + col) * FS + s*16 + half*8]);
                acc = __builtin_amdgcn_mfma_f32_32x32x16_f16(a, Bf[s], acc, 0, 0, 0);
            }

            #pragma unroll
            for (int r = 0; r < 16; ++r) {
                int n = base + eh*32 + (r & 3) + 8*(r >> 2) + 4*half;
                if (n < N_NODES) {
                    float vv = acc[r] + b2v;
                    out[(size_t)n * 64 + nh*32 + col] = vv > 0.f ? vv : 0.f;
                }
            }
        }
    }
}

extern "C" void kernel_launch(void* const* d_in, const int* in_sizes, int n_in,
                              void* d_out, int out_size, void* d_ws, size_t ws_size,
                              hipStream_t stream) {
    const float* x     = (const float*)d_in[0];
    const int*   ei    = (const int*)d_in[1];
    const float* ea    = (const float*)d_in[2];
    const float* u     = (const float*)d_in[3];
    const int*   batch = (const int*)d_in[4];
    const float* W1    = (const float*)d_in[5];
    const float* b1    = (const float*)d_in[6];
    const float* W2    = (const float*)d_in[7];
    const float* b2    = (const float*)d_in[8];
    float* out = (float*)d_out;

    unsigned short* ws_w1t = (unsigned short*)((char*)d_ws + WS_W1T);
    unsigned short* ws_w2t = (unsigned short*)((char*)d_ws + WS_W2T);
    unsigned short* ws_ub  = (unsigned short*)((char*)d_ws + WS_UB);
    unsigned short* ws_xb  = (unsigned short*)((char*)d_ws + WS_XB);

    // Persistent grid: CUs x blocks/CU (occupancy-validated once, cached)
    static int g_blocks = 0;
    if (g_blocks == 0) {
        int maxb = 0;
        if (hipOccupancyMaxActiveBlocksPerMultiprocessor(&maxb, fused_all, 256, 0)
                != hipSuccess || maxb <= 0)
            maxb = 4;
        if (maxb > 6) maxb = 6;
        int cus = 256;
        hipDeviceProp_t prop;
        if (hipGetDeviceProperties(&prop, 0) == hipSuccess && prop.multiProcessorCount > 0)
            cus = prop.multiProcessorCount;
        g_blocks = cus * maxb;
    }

    int phase = -1;
    void* args[] = { (void*)&x, (void*)&ei, (void*)&ea, (void*)&u, (void*)&batch,
                     (void*)&W1, (void*)&b1, (void*)&W2, (void*)&b2,
                     (void*)&ws_w1t, (void*)&ws_w2t, (void*)&ws_ub, (void*)&ws_xb,
                     (void*)&out, (void*)&phase };
    hipError_t err = hipLaunchCooperativeKernel(fused_all, dim3(g_blocks), dim3(256),
                                                args, 0, stream);
    if (err != hipSuccess) {
        (void)hipGetLastError();   // clear sticky error; fall back to 3 launches
        fused_all<<<g_blocks, 256, 0, stream>>>(x, ei, ea, u, batch, W1, b1, W2, b2,
                                                ws_w1t, ws_w2t, ws_ub, ws_xb, out, 0);
        fused_all<<<g_blocks, 256, 0, stream>>>(x, ei, ea, u, batch, W1, b1, W2, b2,
                                                ws_w1t, ws_w2t, ws_ub, ws_xb, out, 1);
        fused_all<<<g_blocks, 256, 0, stream>>>(x, ei, ea, u, batch, W1, b1, W2, b2,
                                                ws_w1t, ws_w2t, ws_ub, ws_xb, out, 2);
    }
}

// Round 8
// 360.071 us; speedup vs baseline: 2.0553x; 2.0553x over previous
//
#include <hip/hip_runtime.h>

// Problem constants (from reference)
constexpr int N_NODES = 100000;
constexpr int N_EDGES = 1000000;
constexpr int D_NODE  = 64;
constexpr int D_EDGE  = 32;
constexpr int D_GLOB  = 32;
constexpr int OUT_DIM = 64;
constexpr int K1 = 2*D_NODE + D_EDGE + D_GLOB; // 192
constexpr int K2 = D_NODE + OUT_DIM + D_GLOB;  // 160

typedef _Float16 f16x8 __attribute__((ext_vector_type(8)));
typedef unsigned short ushort8_t __attribute__((ext_vector_type(8)));
typedef float floatx16 __attribute__((ext_vector_type(16)));

// LDS feature-tile row stride (f16 elems): 400 B rows, 16B-aligned.
constexpr int FS = 200;

// d_ws layout (bytes), all 16B-aligned:
//   [0,     24576)  W1t f16 [64][192]   (transposed: [n][k])
//   [24576, 45056)  W2t f16 [64][160]
//   [45056, 46080)  ub  f16 [16][32]
//   [46080, ...  )  xb  f16 [100000][64]  (12.8 MB)
// agg (f16 [100000][64]) lives INSIDE d_out: row n occupies the first
// 128 B of out row n (256 B). Block-exclusive in node_kernel -> no race.
constexpr size_t WS_W1T = 0;
constexpr size_t WS_W2T = 24576;
constexpr size_t WS_UB  = 45056;
constexpr size_t WS_XB  = 46080;

__device__ inline unsigned pack_f2(float a, float b) {
    auto h = __builtin_amdgcn_cvt_pkrtz(a, b);    // v_cvt_pkrtz_f16_f32
    return __builtin_bit_cast(unsigned, h);
}

// ---------------------------------------------------------------------------
// Prep: f16-convert x, u; f16+transpose W1, W2; zero d_out (agg accumulator).
// The memset dispatch is folded in here (saves one kernel boundary).
// Runs every launch (harness re-poisons d_ws).
// ---------------------------------------------------------------------------
__global__ __launch_bounds__(256) void prep_kernel(
    const float* __restrict__ x, const float* __restrict__ u,
    const float* __restrict__ W1, const float* __restrict__ W2,
    unsigned short* __restrict__ ws_w1t, unsigned short* __restrict__ ws_w2t,
    unsigned short* __restrict__ ws_ub, unsigned short* __restrict__ ws_xb,
    float* __restrict__ out)
{
    const int t = blockIdx.x * 256 + threadIdx.x;
    const int stride = gridDim.x * 256;
    const float4* x4 = (const float4*)x;
    for (int i = t; i < N_NODES * 16; i += stride) {       // x: 1.6M float4
        float4 v = x4[i];
        uint2 pk;
        pk.x = pack_f2(v.x, v.y);
        pk.y = pack_f2(v.z, v.w);
        *(uint2*)&ws_xb[i * 4] = pk;
    }
    const uint4 z = {0, 0, 0, 0};
    uint4* o4 = (uint4*)out;
    for (int i = t; i < N_NODES * 16; i += stride)         // zero agg/out
        o4[i] = z;
    for (int i = t; i < K1 * 64; i += stride) {            // W1 [k][n] -> [n][k]
        int k = i >> 6, n = i & 63;
        _Float16 h = (_Float16)W1[i];
        ws_w1t[n * K1 + k] = __builtin_bit_cast(unsigned short, h);
    }
    for (int i = t; i < K2 * 64; i += stride) {            // W2 [k][n] -> [n][k]
        int k = i >> 6, n = i & 63;
        _Float16 h = (_Float16)W2[i];
        ws_w2t[n * K2 + k] = __builtin_bit_cast(unsigned short, h);
    }
    for (int i = t; i < 16 * D_GLOB; i += stride) {        // u
        _Float16 h = (_Float16)u[i];
        ws_ub[i] = __builtin_bit_cast(unsigned short, h);
    }
}

// ---------------------------------------------------------------------------
// Edge kernel (32x32x16 MFMA, R0 orientation): msg = relu(feat @ W1 + b1),
// D[edge][ch]. Epilogue: msg tile round-trips through LDS (f32 64x64,
// reusing the feat buffer), then each wave re-reads it TRANSPOSED so one
// pk_add_f16 instruction covers all 64 channels of exactly 2 dst rows
// (2 rows x 128B = 2 lines/instr, R0-grade locality, HALF the RMW ops).
// ea gather is index-independent -> issued BEFORE the index barrier.
// 6 blocks/CU (LDS-capped). Blocks EXIT after issuing atomics (fire-and-
// forget stays off the critical path — R7 lesson).
// ---------------------------------------------------------------------------
__global__ __launch_bounds__(256, 6) void edge_kernel(
    const unsigned short* __restrict__ xb, const int* __restrict__ ei,
    const float* __restrict__ ea, const unsigned short* __restrict__ ub,
    const int* __restrict__ batch, const unsigned short* __restrict__ W1t,
    const float* __restrict__ b1, float* __restrict__ out)
{
    __shared__ __align__(16) unsigned short smem[64 * FS]; // 25600 B (feat, then f32 msg[64][64])
    __shared__ int s_dst[64];
    __shared__ int s_src[64];
    __shared__ int s_b[64];

    const int tid  = threadIdx.x;
    const int lane = tid & 63;
    const int wv   = tid >> 6;
    const int tile = blockIdx.x;
    const int eh   = wv >> 1;
    const int nh   = wv & 1;
    const int col  = lane & 31;
    const int half = lane >> 5;
    const float4* ea4 = (const float4*)ea;

    if (tid < 64) {
        int e = tile * 64 + tid;
        int d = ei[N_EDGES + e];            // dst = edge_index[1]
        s_dst[tid] = d;
        s_src[tid] = ei[e];                 // src = edge_index[0]
        s_b[tid]   = batch[d];
    }

    // ea chunks depend only on tile: issue before the index barrier.
    // 256 threads x 1 chunk: el = tid>>2, c = tid&3; K slots [128,160).
    {
        int el = tid >> 2, c = tid & 3;
        float4 v0 = ea4[(tile*64 + el) * 8 + c * 2 + 0];
        float4 v1 = ea4[(tile*64 + el) * 8 + c * 2 + 1];
        uint4 pk;
        pk.x = pack_f2(v0.x, v0.y); pk.y = pack_f2(v0.z, v0.w);
        pk.z = pack_f2(v1.x, v1.y); pk.w = pack_f2(v1.z, v1.w);
        *(uint4*)&smem[el * FS + (16 + c) * 8] = pk;
    }

    // B fragments: B[k][n], n = nh*32+col, k = s*16 + half*8 + j
    f16x8 Wf[12];
    #pragma unroll
    for (int s = 0; s < 12; ++s)
        Wf[s] = __builtin_bit_cast(f16x8,
            *(const ushort8_t*)&W1t[(nh*32 + col) * K1 + s*16 + half*8]);

    // Epilogue channel-pair for this lane (covers ch 2*(lane&31), +1)
    const int chp = (lane & 31) * 2;
    const float2 bv = *(const float2*)&b1[chp];

    __syncthreads();                        // indices visible

    // Gather remaining 20 chunks/edge (x[dst]:8 | x[src]:8 | u:4), 5/thread.
    // K slots: x_dst [0,64), x_src [64,128), u [160,192).
    for (int q = tid; q < 64 * 20; q += 256) {
        int el = q / 20;
        int c  = q - el * 20;
        uint4 pk;
        if (c < 8)       pk = *(const uint4*)&xb[s_dst[el] * 64 + c * 8];
        else if (c < 16) pk = *(const uint4*)&xb[s_src[el] * 64 + (c - 8) * 8];
        else             pk = *(const uint4*)&ub[s_b[el] * 32 + (c - 16) * 8];
        *(uint4*)&smem[el * FS + (c < 16 ? c : c + 4) * 8] = pk;
    }
    __syncthreads();                        // feat visible

    // Compute: A rows = edges (eh*32 + col), B cols = channels -> D[edge][ch]
    floatx16 acc = {0,0,0,0,0,0,0,0,0,0,0,0,0,0,0,0};
    #pragma unroll
    for (int s = 0; s < 12; ++s) {
        f16x8 a = __builtin_bit_cast(f16x8,
            *(const ushort8_t*)&smem[(eh*32 + col) * FS + s*16 + half*8]);
        acc = __builtin_amdgcn_mfma_f32_32x32x16_f16(a, Wf[s], acc, 0, 0, 0);
    }

    // Stage msg tile to LDS (f32 [64 edge][64 ch]); C layout:
    // edge = eh*32 + (r&3)+8*(r>>2)+4*half, ch = nh*32+col.
    __syncthreads();                       // all waves done reading feat tile
    float* smemf = (float*)smem;
    #pragma unroll
    for (int r = 0; r < 16; ++r) {
        int e = eh*32 + (r & 3) + 8*(r >> 2) + 4*half;
        smemf[e * 64 + nh*32 + col] = acc[r];
    }
    __syncthreads();

    // Transposed epilogue: wave wv owns edges [wv*16, wv*16+16); per iter the
    // 64 lanes cover 2 edge rows x 32 channel-pairs -> 2 agg rows, 2 lines.
    #pragma unroll
    for (int it = 0; it < 8; ++it) {
        int e = wv*16 + it*2 + half;
        float2 m = *(const float2*)&smemf[e * 64 + chp];
        float v0 = m.x + bv.x; v0 = v0 > 0.f ? v0 : 0.f;
        float v1 = m.y + bv.y; v1 = v1 > 0.f ? v1 : 0.f;
        unsigned pk = pack_f2(v0, v1);
        unsigned short* p = (unsigned short*)out + (size_t)s_dst[e] * 128 + chp;
        asm volatile("global_atomic_pk_add_f16 %0, %1, off"
                     :: "v"(p), "v"(pk) : "memory");
    }
}

// ---------------------------------------------------------------------------
// Node kernel (32x32x16 MFMA): out = relu([x, agg, u[batch]] @ W2 + b2)
// agg read f16 from the first 128 B of each out row; in-place, row-exclusive
// per block. One 64-node tile per block (tail guarded).
// ---------------------------------------------------------------------------
__global__ __launch_bounds__(256, 6) void node_kernel(
    const unsigned short* __restrict__ xb, const unsigned short* __restrict__ ub,
    const int* __restrict__ batch, const unsigned short* __restrict__ W2t,
    const float* __restrict__ b2, float* __restrict__ out)
{
    __shared__ __align__(16) unsigned short smem[64 * FS];
    __shared__ int s_b[64];

    const int tid  = threadIdx.x;
    const int lane = tid & 63;
    const int wv   = tid >> 6;
    const int base = blockIdx.x * 64;
    const int eh   = wv >> 1;
    const int nh   = wv & 1;
    const int col  = lane & 31;
    const int half = lane >> 5;

    if (tid < 64) {
        int n = base + tid;
        s_b[tid] = (n < N_NODES) ? batch[n] : 0;
    }

    f16x8 Bf[10];
    #pragma unroll
    for (int s = 0; s < 10; ++s)
        Bf[s] = __builtin_bit_cast(f16x8,
            *(const ushort8_t*)&W2t[(nh*32 + col) * K2 + s*16 + half*8]);
    const float b2v = b2[nh*32 + col];

    __syncthreads();

    // Gather: 64 nodes x 20 16B-chunks (x:8 | agg:8 | u:4)
    const unsigned short* aggb = (const unsigned short*)out;
    for (int q = tid; q < 64 * 20; q += 256) {
        int nl = q / 20;
        int c  = q - nl * 20;
        int n  = base + nl;
        uint4 pk;
        if (n >= N_NODES) pk = uint4{0, 0, 0, 0};
        else if (c < 8)   pk = *(const uint4*)&xb[n * 64 + c * 8];
        else if (c < 16)  pk = *(const uint4*)&aggb[(size_t)n * 128 + (c - 8) * 8];
        else              pk = *(const uint4*)&ub[s_b[nl] * 32 + (c - 16) * 8];
        *(uint4*)&smem[nl * FS + c * 8] = pk;
    }
    __syncthreads();

    floatx16 acc = {0,0,0,0,0,0,0,0,0,0,0,0,0,0,0,0};
    #pragma unroll
    for (int s = 0; s < 10; ++s) {
        f16x8 a = __builtin_bit_cast(f16x8,
            *(const ushort8_t*)&smem[(eh*32 + col) * FS + s*16 + half*8]);
        acc = __builtin_amdgcn_mfma_f32_32x32x16_f16(a, Bf[s], acc, 0, 0, 0);
    }

    #pragma unroll
    for (int r = 0; r < 16; ++r) {
        int n = base + eh*32 + (r & 3) + 8*(r >> 2) + 4*half;
        if (n < N_NODES) {
            float vv = acc[r] + b2v;
            out[n * 64 + nh*32 + col] = vv > 0.f ? vv : 0.f;
        }
    }
}

extern "C" void kernel_launch(void* const* d_in, const int* in_sizes, int n_in,
                              void* d_out, int out_size, void* d_ws, size_t ws_size,
                              hipStream_t stream) {
    const float* x     = (const float*)d_in[0];
    const int*   ei    = (const int*)d_in[1];
    const float* ea    = (const float*)d_in[2];
    const float* u     = (const float*)d_in[3];
    const int*   batch = (const int*)d_in[4];
    const float* W1    = (const float*)d_in[5];
    const float* b1    = (const float*)d_in[6];
    const float* W2    = (const float*)d_in[7];
    const float* b2    = (const float*)d_in[8];
    float* out = (float*)d_out;

    unsigned short* ws_w1t = (unsigned short*)((char*)d_ws + WS_W1T);
    unsigned short* ws_w2t = (unsigned short*)((char*)d_ws + WS_W2T);
    unsigned short* ws_ub  = (unsigned short*)((char*)d_ws + WS_UB);
    unsigned short* ws_xb  = (unsigned short*)((char*)d_ws + WS_XB);

    // prep also zeroes d_out (agg f16 accumulator lives in its low halves)
    prep_kernel<<<2048, 256, 0, stream>>>(x, u, W1, W2, ws_w1t, ws_w2t,
                                          ws_ub, ws_xb, out);
    edge_kernel<<<N_EDGES / 64, 256, 0, stream>>>(ws_xb, ei, ea, ws_ub, batch, ws_w1t, b1, out);
    node_kernel<<<(N_NODES + 63) / 64, 256, 0, stream>>>(ws_xb, ws_ub, batch, ws_w2t, b2, out);
}